// Round 6
// baseline (49.037 us; speedup 1.0000x reference)
//
#include <hip/hip_runtime.h>
#include <math.h>

#define L_SEQ  16384
#define CHN    512
#define S_DIM  128
#define NPRE   1024             // rows whose dt we compute speculatively
#define NBLK   1024             // K2 grid: 4 blocks/CU via launch_bounds -> all co-resident
#define RPB    (L_SEQ / NBLK)   // 16 rows (32 KB) contiguous slab per block
// exp(A[s]*E) == 0.0f in f32 for all s (A <= -1) once E >= 104; the reference's
// pairwise prefix product underflows identically (residual <= ~1e-43 vs
// threshold 1.7e-2), so rows past the cutoff are exact zeros on both sides.
#define E_CUT  104.0f

typedef float v4f __attribute__((ext_vector_type(4)));   // clang vector: OK for nontemporal
typedef float v2f __attribute__((ext_vector_type(2)));

static __device__ __forceinline__ float softplus_f(float z) {
    return (z > 20.f) ? z : log1pf(expf(z));
}

// ---------------- K1: dt[l] for l < NPRE (wave per row) + flag reset --------
__global__ __launch_bounds__(256) void k_dt(const float* __restrict__ x,
                                            const float* __restrict__ Wdt,
                                            const float* __restrict__ bdt,
                                            float* __restrict__ dt,
                                            int*   __restrict__ flag)
{
    // stream order guarantees K2 sees this reset (kernel-boundary coherence)
    if (blockIdx.x == 0 && threadIdx.x == 0) *flag = 0;

    const int wave = threadIdx.x >> 6;
    const int lane = threadIdx.x & 63;
    const int row  = blockIdx.x * 4 + wave;

    const float4* xr = (const float4*)(x + (size_t)row * CHN);
    const float4* w4 = (const float4*)Wdt;

    float acc = 0.f;
#pragma unroll
    for (int i = 0; i < 2; ++i) {   // 64 lanes * 2 float4 = 512 floats
        float4 xv = xr[lane + 64 * i];
        float4 wv = w4[lane + 64 * i];
        acc = fmaf(xv.x, wv.x, acc); acc = fmaf(xv.y, wv.y, acc);
        acc = fmaf(xv.z, wv.z, acc); acc = fmaf(xv.w, wv.w, acc);
    }
#pragma unroll
    for (int off = 32; off; off >>= 1) acc += __shfl_down(acc, off);

    if (lane == 0) dt[row] = softplus_f(acc + bdt[0]);
}

// ---------------- K2: scan (block 0) -> flag; fill + active GEMV ------------
__global__ __launch_bounds__(256, 4) void k_main(const float* __restrict__ x,
                                                 const float* __restrict__ logA,
                                                 const float* __restrict__ WB,
                                                 const float* __restrict__ WC,
                                                 const float* __restrict__ Wdt,
                                                 const float* __restrict__ bdt,
                                                 float* __restrict__ dt,
                                                 float* __restrict__ E,
                                                 int*   __restrict__ n_p,
                                                 int*   __restrict__ flag,
                                                 float* __restrict__ out)
{
    const int b = blockIdx.x;
    const int t = threadIdx.x;

    if (b == 0) {
        // ---- single-wave scan of dt[0:NPRE) -> E, n; inline rare fallback --
        if (t < 64) {
            const int lane = t;
            const int PER  = NPRE / 64;                    // 16

            float v[PER], ex[PER];
            const float4* dt4 = (const float4*)dt;
#pragma unroll
            for (int i = 0; i < PER / 4; ++i) {
                float4 q = dt4[lane * (PER / 4) + i];
                v[4*i+0] = q.x; v[4*i+1] = q.y; v[4*i+2] = q.z; v[4*i+3] = q.w;
            }
            float run = 0.f;
#pragma unroll
            for (int i = 0; i < PER; ++i) { ex[i] = run; run += v[i]; }

            float incl = run;                              // shuffle inclusive scan
#pragma unroll
            for (int off = 1; off < 64; off <<= 1) {
                float o = __shfl_up(incl, off);
                if (lane >= off) incl += o;
            }
            const float excl  = incl - run;
            const float total = __shfl(incl, 63);

            float4* E4 = (float4*)E;
#pragma unroll
            for (int i = 0; i < PER / 4; ++i)
                E4[lane * (PER / 4) + i] =
                    make_float4(excl + ex[4*i],   excl + ex[4*i+1],
                                excl + ex[4*i+2], excl + ex[4*i+3]);

            int cnt = 0;
#pragma unroll
            for (int i = 0; i < PER; ++i) cnt += (excl + ex[i] < E_CUT) ? 1 : 0;
#pragma unroll
            for (int off = 32; off; off >>= 1) cnt += __shfl_down(cnt, off);
            int n = __shfl(cnt, 0);

            if (n == NPRE) {   // cutoff not reached: serial extension (never taken here)
                float running = total;
                for (int l = NPRE; l < L_SEQ && running < E_CUT; ++l) {
                    const float4* xr = (const float4*)(x + (size_t)l * CHN);
                    const float4* w4 = (const float4*)Wdt;
                    float acc = 0.f;
#pragma unroll
                    for (int i = 0; i < 2; ++i) {
                        float4 xv = xr[lane + 64 * i];
                        float4 wv = w4[lane + 64 * i];
                        acc = fmaf(xv.x, wv.x, acc); acc = fmaf(xv.y, wv.y, acc);
                        acc = fmaf(xv.z, wv.z, acc); acc = fmaf(xv.w, wv.w, acc);
                    }
#pragma unroll
                    for (int off = 32; off; off >>= 1) acc += __shfl_down(acc, off);
                    float d = softplus_f(__shfl(acc, 0) + bdt[0]);
                    if (lane == 0) { E[l] = running; dt[l] = d; }
                    running += d;
                    ++n;
                }
            }
            if (lane == 0) {
                n_p[0] = n;
                __threadfence();   // make E/dt/n visible device-wide, then release
                __hip_atomic_store(flag, 1, __ATOMIC_RELEASE, __HIP_MEMORY_SCOPE_AGENT);
            }
        }
        __syncthreads();           // waves 1..3 of block 0 wait for wave 0
    } else {
        if (t == 0) {
            while (__hip_atomic_load(flag, __ATOMIC_ACQUIRE,
                                     __HIP_MEMORY_SCOPE_AGENT) == 0)
                __builtin_amdgcn_s_sleep(8);
        }
        __syncthreads();
    }

    const int n = n_p[0];

    // ---- contiguous slab zero-fill (dead rows only), XCD-contiguous swizzle
    {
        const int s  = ((b & 7) << 7) | (b >> 3);   // bijective on [0,1024)
        const int r0 = s * RPB;
        const int lo = (r0 > n) ? r0 : n;           // active rows are a prefix
        const int hi = r0 + RPB;
        if (lo < hi) {
            v4f* dst = (v4f*)(out + (size_t)lo * CHN);
            const int cnt = (hi - lo) * (CHN / 4);  // <= 2048 vectors
            const v4f z = {0.f, 0.f, 0.f, 0.f};
            for (int i = t; i < cnt; i += 256)
                __builtin_nontemporal_store(z, dst + i);
        }
    }

    // ---- active rows: fused GEMV(B,C) + einsum scalar + row write ----------
    const int g  = t >> 5;          // channel group 0..7
    const int s4 = t & 31;          // state quad: states 4*s4 .. 4*s4+3

    __shared__ float  xs[CHN];
    __shared__ float4 redB[8][32];
    __shared__ float4 redC[8][32];
    __shared__ float  scal;

    const float4* wb = (const float4*)WB;   // WB[c][4*s4..] == wb[c*32 + s4]
    const float4* wc = (const float4*)WC;

    for (int l = b; l < n; l += NBLK) {
        ((float2*)xs)[t] = ((const float2*)(x + (size_t)l * CHN))[t];
        __syncthreads();

        float4 aB = make_float4(0.f, 0.f, 0.f, 0.f);
        float4 aC = make_float4(0.f, 0.f, 0.f, 0.f);
#pragma unroll 8
        for (int c = g; c < CHN; c += 8) {
            const float  xc = xs[c];
            const float4 bq = wb[c * 32 + s4];
            const float4 cq = wc[c * 32 + s4];
            aB.x = fmaf(xc, bq.x, aB.x);  aB.y = fmaf(xc, bq.y, aB.y);
            aB.z = fmaf(xc, bq.z, aB.z);  aB.w = fmaf(xc, bq.w, aB.w);
            aC.x = fmaf(xc, cq.x, aC.x);  aC.y = fmaf(xc, cq.y, aC.y);
            aC.z = fmaf(xc, cq.z, aC.z);  aC.w = fmaf(xc, cq.w, aC.w);
        }
        redB[g][s4] = aB;
        redC[g][s4] = aC;
        __syncthreads();

        if (t < 32) {
            float4 B = redB[0][t], C = redC[0][t];
#pragma unroll
            for (int k = 1; k < 8; ++k) {
                float4 bq = redB[k][t], cq = redC[k][t];
                B.x += bq.x; B.y += bq.y; B.z += bq.z; B.w += bq.w;
                C.x += cq.x; C.y += cq.y; C.z += cq.z; C.w += cq.w;
            }
            const float  e   = E[l];
            const float  dtl = dt[l];
            const float4 la  = ((const float4*)logA)[t];

            float con = 0.f;
            float a = -expf(la.x);
            con = fmaf(C.x * expf(a * e), expm1f(a * dtl) * B.x / a, con);
            a = -expf(la.y);
            con = fmaf(C.y * expf(a * e), expm1f(a * dtl) * B.y / a, con);
            a = -expf(la.z);
            con = fmaf(C.z * expf(a * e), expm1f(a * dtl) * B.z / a, con);
            a = -expf(la.w);
            con = fmaf(C.w * expf(a * e), expm1f(a * dtl) * B.w / a, con);
#pragma unroll
            for (int off = 16; off; off >>= 1) con += __shfl_down(con, off);
            if (t == 0) scal = con;
        }
        __syncthreads();

        const float  sc = scal;
        const float2 xv = ((float2*)xs)[t];
        v2f ov = {sc * xv.x, sc * xv.y};
        __builtin_nontemporal_store(ov, (v2f*)(out + (size_t)l * CHN) + t);
        __syncthreads();   // xs/red reused if n > NBLK
    }
}

// -----------------------------------------------------------------------------
extern "C" void kernel_launch(void* const* d_in, const int* in_sizes, int n_in,
                              void* d_out, int out_size, void* d_ws, size_t ws_size,
                              hipStream_t stream)
{
    const float* x    = (const float*)d_in[0];
    const float* logA = (const float*)d_in[1];
    const float* WB   = (const float*)d_in[2];
    const float* WC   = (const float*)d_in[3];
    const float* Wdt  = (const float*)d_in[4];
    const float* bdt  = (const float*)d_in[5];
    float* out = (float*)d_out;

    float* dt   = (float*)d_ws;                 // L_SEQ floats (only [0,n) used)
    float* E    = dt + L_SEQ;                   // L_SEQ floats
    int*   n_p  = (int*)(E + L_SEQ);
    int*   flag = n_p + 1;

    k_dt  <<<NPRE / 4, 256, 0, stream>>>(x, Wdt, bdt, dt, flag);
    k_main<<<NBLK,     256, 0, stream>>>(x, logA, WB, WC, Wdt, bdt,
                                         dt, E, n_p, flag, out);
}

// Round 7
// 34.503 us; speedup vs baseline: 1.4212x; 1.4212x over previous
//
#include <hip/hip_runtime.h>
#include <math.h>

#define L_SEQ  16384
#define CHN    512
#define S_DIM  128
#define NPRE   1024             // rows whose dt we compute speculatively
#define FBLK   2048             // fill grid: 2048*256 threads * 4 float4 = whole output
// exp(A[s]*E) == 0.0f in f32 for all s (A <= -1) once E >= 104; the reference's
// pairwise prefix product underflows identically (residual <= ~1e-43 vs
// threshold 1.7e-2), so rows past the cutoff are exact zeros on both sides.
#define E_CUT  104.0f

static __device__ __forceinline__ float softplus_f(float z) {
    return (z > 20.f) ? z : log1pf(expf(z));
}

// ---- K1: zero-fill ALL of out (harness-fill access pattern) + dt[0:NPRE) ---
// The fill has no dependence on the scan: active rows are overwritten by K3.
__global__ __launch_bounds__(256) void k_fill_dt(const float* __restrict__ x,
                                                 const float* __restrict__ Wdt,
                                                 const float* __restrict__ bdt,
                                                 float* __restrict__ dt,
                                                 float* __restrict__ out)
{
    const int b = blockIdx.x;
    const int t = threadIdx.x;

    // grid-stride float4 fill: 2,097,152 vectors / 524,288 threads = 4 each
    {
        float4* o4 = (float4*)out;
        const float4 z = make_float4(0.f, 0.f, 0.f, 0.f);
        size_t i = (size_t)b * 256 + t;
#pragma unroll
        for (int k = 0; k < 4; ++k) {
            o4[i] = z;
            i += (size_t)FBLK * 256;
        }
    }

    // blocks 0..255: dt for rows 0..NPRE-1 (wave per row)
    if (b < NPRE / 4) {
        const int wave = t >> 6, lane = t & 63;
        const int row  = b * 4 + wave;
        const float4* xr = (const float4*)(x + (size_t)row * CHN);
        const float4* w4 = (const float4*)Wdt;
        float acc = 0.f;
#pragma unroll
        for (int i = 0; i < 2; ++i) {      // 64 lanes * 2 float4 = 512 floats
            float4 xv = xr[lane + 64 * i];
            float4 wv = w4[lane + 64 * i];
            acc = fmaf(xv.x, wv.x, acc); acc = fmaf(xv.y, wv.y, acc);
            acc = fmaf(xv.z, wv.z, acc); acc = fmaf(xv.w, wv.w, acc);
        }
#pragma unroll
        for (int off = 32; off; off >>= 1) acc += __shfl_down(acc, off);
        if (lane == 0) dt[row] = softplus_f(acc + bdt[0]);
    }
}

// ------- K2: single-wave scan of dt[0:NPRE) -> E, n; inline rare fallback ---
__global__ __launch_bounds__(64) void k_scan_fb(const float* __restrict__ x,
                                                const float* __restrict__ Wdt,
                                                const float* __restrict__ bdt,
                                                float* __restrict__ dt,
                                                float* __restrict__ E,
                                                int*   __restrict__ n_p)
{
    const int lane = threadIdx.x;        // 64 lanes x 16 values = NPRE
    const int PER  = NPRE / 64;          // 16

    float v[PER], ex[PER];
    const float4* dt4 = (const float4*)dt;
#pragma unroll
    for (int i = 0; i < PER / 4; ++i) {
        float4 q = dt4[lane * (PER / 4) + i];
        v[4*i+0] = q.x; v[4*i+1] = q.y; v[4*i+2] = q.z; v[4*i+3] = q.w;
    }

    float run = 0.f;
#pragma unroll
    for (int i = 0; i < PER; ++i) { ex[i] = run; run += v[i]; }

    float incl = run;                    // inclusive shuffle-scan of lane totals
#pragma unroll
    for (int off = 1; off < 64; off <<= 1) {
        float o = __shfl_up(incl, off);
        if (lane >= off) incl += o;
    }
    const float excl  = incl - run;
    const float total = __shfl(incl, 63);

    float4* E4 = (float4*)E;
#pragma unroll
    for (int i = 0; i < PER / 4; ++i)
        E4[lane * (PER / 4) + i] = make_float4(excl + ex[4*i],   excl + ex[4*i+1],
                                               excl + ex[4*i+2], excl + ex[4*i+3]);

    int cnt = 0;
#pragma unroll
    for (int i = 0; i < PER; ++i) cnt += (excl + ex[i] < E_CUT) ? 1 : 0;
#pragma unroll
    for (int off = 32; off; off >>= 1) cnt += __shfl_down(cnt, off);
    int n = __shfl(cnt, 0);

    if (n == NPRE) {   // cutoff not reached in NPRE: serial extension
        float running = total;
        for (int l = NPRE; l < L_SEQ && running < E_CUT; ++l) {
            const float4* xr = (const float4*)(x + (size_t)l * CHN);
            const float4* w4 = (const float4*)Wdt;
            float acc = 0.f;
#pragma unroll
            for (int i = 0; i < 2; ++i) {
                float4 xv = xr[lane + 64 * i];
                float4 wv = w4[lane + 64 * i];
                acc = fmaf(xv.x, wv.x, acc); acc = fmaf(xv.y, wv.y, acc);
                acc = fmaf(xv.z, wv.z, acc); acc = fmaf(xv.w, wv.w, acc);
            }
#pragma unroll
            for (int off = 32; off; off >>= 1) acc += __shfl_down(acc, off);
            float d = softplus_f(__shfl(acc, 0) + bdt[0]);
            if (lane == 0) { E[l] = running; dt[l] = d; }
            running += d;
            ++n;
        }
    }
    if (lane == 0) n_p[0] = n;
}

// ---------------- K3: ACTIVE rows only (block per row, ~n blocks work) ------
// out[l,:] = scalar[l] * x[l,:]
// scalar[l] = sum_s C[l,s] * exp(A[s]*E[l]) * expm1(A[s]*dt[l]) * B[l,s] / A[s]
__global__ __launch_bounds__(256) void k_active(const float* __restrict__ x,
                                                const float* __restrict__ logA,
                                                const float* __restrict__ WB,
                                                const float* __restrict__ WC,
                                                const float* __restrict__ dt,
                                                const float* __restrict__ E,
                                                const int* __restrict__ n_p,
                                                float* __restrict__ out)
{
    const int n  = n_p[0];
    const int t  = threadIdx.x;
    const int g  = t >> 5;          // channel group 0..7
    const int s4 = t & 31;          // state quad: states 4*s4 .. 4*s4+3

    __shared__ float  xs[CHN];
    __shared__ float4 redB[8][32];
    __shared__ float4 redC[8][32];
    __shared__ float  scal;

    const float4* wb = (const float4*)WB;   // WB[c][4*s4..] == wb[c*32 + s4]
    const float4* wc = (const float4*)WC;

    for (int l = blockIdx.x; l < n; l += gridDim.x) {
        ((float2*)xs)[t] = ((const float2*)(x + (size_t)l * CHN))[t];
        __syncthreads();

        float4 aB = make_float4(0.f, 0.f, 0.f, 0.f);
        float4 aC = make_float4(0.f, 0.f, 0.f, 0.f);
#pragma unroll 8
        for (int c = g; c < CHN; c += 8) {
            const float  xc = xs[c];
            const float4 bq = wb[c * 32 + s4];
            const float4 cq = wc[c * 32 + s4];
            aB.x = fmaf(xc, bq.x, aB.x);  aB.y = fmaf(xc, bq.y, aB.y);
            aB.z = fmaf(xc, bq.z, aB.z);  aB.w = fmaf(xc, bq.w, aB.w);
            aC.x = fmaf(xc, cq.x, aC.x);  aC.y = fmaf(xc, cq.y, aC.y);
            aC.z = fmaf(xc, cq.z, aC.z);  aC.w = fmaf(xc, cq.w, aC.w);
        }
        redB[g][s4] = aB;
        redC[g][s4] = aC;
        __syncthreads();

        if (t < 32) {
            float4 B = redB[0][t], C = redC[0][t];
#pragma unroll
            for (int k = 1; k < 8; ++k) {
                float4 bq = redB[k][t], cq = redC[k][t];
                B.x += bq.x; B.y += bq.y; B.z += bq.z; B.w += bq.w;
                C.x += cq.x; C.y += cq.y; C.z += cq.z; C.w += cq.w;
            }
            const float  e   = E[l];
            const float  dtl = dt[l];
            const float4 la  = ((const float4*)logA)[t];

            float con = 0.f;
            float a = -expf(la.x);
            con = fmaf(C.x * expf(a * e), expm1f(a * dtl) * B.x / a, con);
            a = -expf(la.y);
            con = fmaf(C.y * expf(a * e), expm1f(a * dtl) * B.y / a, con);
            a = -expf(la.z);
            con = fmaf(C.z * expf(a * e), expm1f(a * dtl) * B.z / a, con);
            a = -expf(la.w);
            con = fmaf(C.w * expf(a * e), expm1f(a * dtl) * B.w / a, con);
#pragma unroll
            for (int off = 16; off; off >>= 1) con += __shfl_down(con, off);
            if (t == 0) scal = con;
        }
        __syncthreads();

        const float  sc = scal;
        const float2 xv = ((float2*)xs)[t];
        ((float2*)(out + (size_t)l * CHN))[t] = make_float2(sc * xv.x, sc * xv.y);
        __syncthreads();   // xs/red reused if n > gridDim.x
    }
}

// -----------------------------------------------------------------------------
extern "C" void kernel_launch(void* const* d_in, const int* in_sizes, int n_in,
                              void* d_out, int out_size, void* d_ws, size_t ws_size,
                              hipStream_t stream)
{
    const float* x    = (const float*)d_in[0];
    const float* logA = (const float*)d_in[1];
    const float* WB   = (const float*)d_in[2];
    const float* WC   = (const float*)d_in[3];
    const float* Wdt  = (const float*)d_in[4];
    const float* bdt  = (const float*)d_in[5];
    float* out = (float*)d_out;

    float* dt  = (float*)d_ws;                  // L_SEQ floats (only [0,n) used)
    float* E   = dt + L_SEQ;                    // L_SEQ floats
    int*   n_p = (int*)(E + L_SEQ);

    k_fill_dt<<<FBLK, 256, 0, stream>>>(x, Wdt, bdt, dt, out);
    k_scan_fb<<<1,    64,  0, stream>>>(x, Wdt, bdt, dt, E, n_p);
    k_active <<<256,  256, 0, stream>>>(x, logA, WB, WC, dt, E, n_p, out);
}

// Round 8
// 32.357 us; speedup vs baseline: 1.5155x; 1.0663x over previous
//
#include <hip/hip_runtime.h>
#include <math.h>

#define L_SEQ  16384
#define CHN    512
#define S_DIM  128
#define NPRE   1024             // rows whose dt we compute speculatively
#define FBLK   2048             // fill grid: 2048*256 threads * 4 float4 = whole output
#define ABLK   256              // active-kernel grid
// exp(A[s]*E) == 0.0f in f32 for all s (A <= -1) once E >= 104; the reference's
// pairwise prefix product underflows identically (residual <= ~1e-43 vs
// threshold 1.7e-2), so rows past the cutoff are exact zeros on both sides.
#define E_CUT  104.0f

static __device__ __forceinline__ float softplus_f(float z) {
    return (z > 20.f) ? z : log1pf(expf(z));
}

// ---- K1: zero-fill ALL of out (grid-stride float4) + dt[0:NPRE) ------------
// The fill has no dependence on the scan: active rows are overwritten by K2.
__global__ __launch_bounds__(256) void k_fill_dt(const float* __restrict__ x,
                                                 const float* __restrict__ Wdt,
                                                 const float* __restrict__ bdt,
                                                 float* __restrict__ dt,
                                                 float* __restrict__ out)
{
    const int b = blockIdx.x;
    const int t = threadIdx.x;

    // grid-stride float4 fill: 2,097,152 vectors / 524,288 threads = 4 each
    {
        float4* o4 = (float4*)out;
        const float4 z = make_float4(0.f, 0.f, 0.f, 0.f);
        size_t i = (size_t)b * 256 + t;
#pragma unroll
        for (int k = 0; k < 4; ++k) {
            o4[i] = z;
            i += (size_t)FBLK * 256;
        }
    }

    // blocks 0..255: dt for rows 0..NPRE-1 (wave per row)
    if (b < NPRE / 4) {
        const int wave = t >> 6, lane = t & 63;
        const int row  = b * 4 + wave;
        const float4* xr = (const float4*)(x + (size_t)row * CHN);
        const float4* w4 = (const float4*)Wdt;
        float acc = 0.f;
#pragma unroll
        for (int i = 0; i < 2; ++i) {      // 64 lanes * 2 float4 = 512 floats
            float4 xv = xr[lane + 64 * i];
            float4 wv = w4[lane + 64 * i];
            acc = fmaf(xv.x, wv.x, acc); acc = fmaf(xv.y, wv.y, acc);
            acc = fmaf(xv.z, wv.z, acc); acc = fmaf(xv.w, wv.w, acc);
        }
#pragma unroll
        for (int off = 32; off; off >>= 1) acc += __shfl_down(acc, off);
        if (lane == 0) dt[row] = softplus_f(acc + bdt[0]);
    }
}

// ---- K2: per-block private scan of dt[0:NPRE) -> E_s, n; then active GEMV --
// out[l,:] = scalar[l] * x[l,:]
// scalar[l] = sum_s C[l,s] * exp(A[s]*E[l]) * expm1(A[s]*dt[l]) * B[l,s] / A[s]
__global__ __launch_bounds__(256) void k_scan_active(const float* __restrict__ x,
                                                     const float* __restrict__ logA,
                                                     const float* __restrict__ WB,
                                                     const float* __restrict__ WC,
                                                     const float* __restrict__ Wdt,
                                                     const float* __restrict__ bdt,
                                                     float* __restrict__ dtg,
                                                     float* __restrict__ Eg,
                                                     float* __restrict__ out)
{
    const int t    = threadIdx.x;
    const int lane = t & 63;
    const int wid  = t >> 6;

    __shared__ float  dt_s[NPRE];
    __shared__ float  E_s[NPRE];
    __shared__ float  wsum[4];
    __shared__ int    n_s;
    __shared__ float  xs[CHN];
    __shared__ float4 redB[8][32];
    __shared__ float4 redC[8][32];
    __shared__ float  scal;

    // ---- private scan: 256 threads x 4 dt values ---------------------------
    if (t == 0) n_s = 0;
    const float4 q = ((const float4*)dtg)[t];
    const float tsum = q.x + q.y + q.z + q.w;

    float incl = tsum;                       // wave inclusive shuffle-scan
#pragma unroll
    for (int off = 1; off < 64; off <<= 1) {
        float o = __shfl_up(incl, off);
        if (lane >= off) incl += o;
    }
    if (lane == 63) wsum[wid] = incl;
    __syncthreads();

    float woff = 0.f;
    for (int w = 0; w < wid; ++w) woff += wsum[w];
    const float excl = woff + incl - tsum;   // exclusive prefix for this thread

    dt_s[4*t+0] = q.x;  dt_s[4*t+1] = q.y;  dt_s[4*t+2] = q.z;  dt_s[4*t+3] = q.w;
    E_s[4*t+0] = excl;
    E_s[4*t+1] = excl + q.x;
    E_s[4*t+2] = excl + q.x + q.y;
    E_s[4*t+3] = excl + q.x + q.y + q.z;

    int cnt = (E_s[4*t+0] < E_CUT) + (E_s[4*t+1] < E_CUT)
            + (E_s[4*t+2] < E_CUT) + (E_s[4*t+3] < E_CUT);
#pragma unroll
    for (int off = 32; off; off >>= 1) cnt += __shfl_down(cnt, off);
    if (lane == 0) atomicAdd(&n_s, cnt);
    __syncthreads();
    int n = n_s;

    // ---- rare fallback: cutoff not reached in NPRE (never taken here) ------
    if (n == NPRE) {
        if (wid == 0) {        // wave 0 serial walk; identical in every block
            float running = E_s[NPRE - 1] + dt_s[NPRE - 1];
            int nn = NPRE;
            for (int l = NPRE; l < L_SEQ && running < E_CUT; ++l) {
                const float4* xr = (const float4*)(x + (size_t)l * CHN);
                const float4* w4 = (const float4*)Wdt;
                float acc = 0.f;
#pragma unroll
                for (int i = 0; i < 2; ++i) {
                    float4 xv = xr[lane + 64 * i];
                    float4 wv = w4[lane + 64 * i];
                    acc = fmaf(xv.x, wv.x, acc); acc = fmaf(xv.y, wv.y, acc);
                    acc = fmaf(xv.z, wv.z, acc); acc = fmaf(xv.w, wv.w, acc);
                }
#pragma unroll
                for (int off = 32; off; off >>= 1) acc += __shfl_down(acc, off);
                float d = softplus_f(__shfl(acc, 0) + bdt[0]);
                if (lane == 0) { Eg[l] = running; dtg[l] = d; }  // identical dup writes
                running += d;
                ++nn;
            }
            if (lane == 0) n_s = nn;
        }
        __threadfence_block();
        __syncthreads();
        n = n_s;
    }

    // ---- active rows: fused GEMV(B,C) + einsum scalar + row write ----------
    const int g  = t >> 5;          // channel group 0..7
    const int s4 = t & 31;          // state quad: states 4*s4 .. 4*s4+3

    const float4* wb = (const float4*)WB;   // WB[c][4*s4..] == wb[c*32 + s4]
    const float4* wc = (const float4*)WC;

    for (int l = blockIdx.x; l < n; l += gridDim.x) {
        ((float2*)xs)[t] = ((const float2*)(x + (size_t)l * CHN))[t];
        __syncthreads();

        float4 aB = make_float4(0.f, 0.f, 0.f, 0.f);
        float4 aC = make_float4(0.f, 0.f, 0.f, 0.f);
#pragma unroll 8
        for (int c = g; c < CHN; c += 8) {
            const float  xc = xs[c];
            const float4 bq = wb[c * 32 + s4];
            const float4 cq = wc[c * 32 + s4];
            aB.x = fmaf(xc, bq.x, aB.x);  aB.y = fmaf(xc, bq.y, aB.y);
            aB.z = fmaf(xc, bq.z, aB.z);  aB.w = fmaf(xc, bq.w, aB.w);
            aC.x = fmaf(xc, cq.x, aC.x);  aC.y = fmaf(xc, cq.y, aC.y);
            aC.z = fmaf(xc, cq.z, aC.z);  aC.w = fmaf(xc, cq.w, aC.w);
        }
        redB[g][s4] = aB;
        redC[g][s4] = aC;
        __syncthreads();

        if (t < 32) {
            float4 B = redB[0][t], C = redC[0][t];
#pragma unroll
            for (int k = 1; k < 8; ++k) {
                float4 bq = redB[k][t], cq = redC[k][t];
                B.x += bq.x; B.y += bq.y; B.z += bq.z; B.w += bq.w;
                C.x += cq.x; C.y += cq.y; C.z += cq.z; C.w += cq.w;
            }
            const float  e   = (l < NPRE) ? E_s[l]  : Eg[l];
            const float  dtl = (l < NPRE) ? dt_s[l] : dtg[l];
            const float4 la  = ((const float4*)logA)[t];

            float con = 0.f;
            float a = -expf(la.x);
            con = fmaf(C.x * expf(a * e), expm1f(a * dtl) * B.x / a, con);
            a = -expf(la.y);
            con = fmaf(C.y * expf(a * e), expm1f(a * dtl) * B.y / a, con);
            a = -expf(la.z);
            con = fmaf(C.z * expf(a * e), expm1f(a * dtl) * B.z / a, con);
            a = -expf(la.w);
            con = fmaf(C.w * expf(a * e), expm1f(a * dtl) * B.w / a, con);
#pragma unroll
            for (int off = 16; off; off >>= 1) con += __shfl_down(con, off);
            if (t == 0) scal = con;
        }
        __syncthreads();

        const float  sc = scal;
        const float2 xv = ((float2*)xs)[t];
        ((float2*)(out + (size_t)l * CHN))[t] = make_float2(sc * xv.x, sc * xv.y);
        __syncthreads();   // xs/red reused if n > gridDim.x
    }
}

// -----------------------------------------------------------------------------
extern "C" void kernel_launch(void* const* d_in, const int* in_sizes, int n_in,
                              void* d_out, int out_size, void* d_ws, size_t ws_size,
                              hipStream_t stream)
{
    const float* x    = (const float*)d_in[0];
    const float* logA = (const float*)d_in[1];
    const float* WB   = (const float*)d_in[2];
    const float* WC   = (const float*)d_in[3];
    const float* Wdt  = (const float*)d_in[4];
    const float* bdt  = (const float*)d_in[5];
    float* out = (float*)d_out;

    float* dt = (float*)d_ws;                   // L_SEQ floats (only [0,n) used)
    float* E  = dt + L_SEQ;                     // L_SEQ floats (fallback spill)

    k_fill_dt    <<<FBLK, 256, 0, stream>>>(x, Wdt, bdt, dt, out);
    k_scan_active<<<ABLK, 256, 0, stream>>>(x, logA, WB, WC, Wdt, bdt,
                                            dt, E, out);
}